// Round 2
// 771.872 us; speedup vs baseline: 1.0887x; 1.0887x over previous
//
#include <hip/hip_runtime.h>
#include <hip/hip_bf16.h>
#include <math.h>

using bf16 = __hip_bfloat16;
typedef __attribute__((ext_vector_type(8))) short short8;   // 8 bf16 (4 VGPRs)
typedef __attribute__((ext_vector_type(4))) short short4v;  // 4 bf16 (8 B)
typedef __attribute__((ext_vector_type(4))) float f32x4;    // MFMA accumulator / f32 loads

static __device__ __forceinline__ bf16 f2b(float x) { return __float2bfloat16(x); }
static __device__ __forceinline__ short f2bs(float x) {
  bf16 h = __float2bfloat16(x);
  return *reinterpret_cast<short*>(&h);
}

#define MFMA16(a, b, c) __builtin_amdgcn_mfma_f32_16x16x32_bf16((a), (b), (c), 0, 0, 0)

// Problem constants
#define NB 8
#define CDIM 192
#define NTOK 16384            // 128*128
#define CN ((size_t)CDIM * NTOK)

// ---------------------------------------------------------------------------
// W pre-convert: Wq,Wk fp32 -> bf16 [2][192*192]
// ---------------------------------------------------------------------------
__global__ __launch_bounds__(256) void convert_w(const float* __restrict__ Wq,
                                                 const float* __restrict__ Wk,
                                                 bf16* __restrict__ Wqk) {
  const int e = (blockIdx.x * 256 + threadIdx.x) * 4;   // 72 blocks -> 73728 elems
  const float* src = (e < CDIM * CDIM) ? (Wq + e) : (Wk + (e - CDIM * CDIM));
  f32x4 v = *reinterpret_cast<const f32x4*>(src);
  short4v w;
  w[0] = f2bs(v[0]); w[1] = f2bs(v[1]); w[2] = f2bs(v[2]); w[3] = f2bs(v[3]);
  *reinterpret_cast<short4v*>(Wqk + e) = w;
}

// ---------------------------------------------------------------------------
// GEMM: OUT[o,n] = sum_c W[o,c] * X[c,n] + bias[o]
// M=192 (full), Nt=64 per block, K=192.
// Orientation: D rows = tokens, cols = o  (mfma(x_frag, w_frag, acc)) so each
// lane holds 4 consecutive tokens of one o-row -> vectorized stores.
// mode 0: 4 projections (q1p,q2p,k1,k2) x 8 batches (z in [0,32)), bf16 out
// mode 1: final fused GEMM, per (pair,b) bf16 weight Mbuf, fp32 out
// ---------------------------------------------------------------------------
struct GemmParams {
  const float *q1, *q2, *x1, *x2;
  const bf16* Wqk;   // [2][192*192] bf16 (pre-converted Wq, Wk)
  const float *bq, *bk;
  bf16* proj;        // [4][8][192*16384] bf16
  const bf16* M;     // [16][192*192] bf16
  const float* Bf;   // [16][192]
  float* out;        // [16][192*16384] fp32 (= d_out)
  int mode;
};

__global__ __launch_bounds__(256, 4) void gemm_oc(GemmParams P) {
  const int tid = threadIdx.x;
  const int z = blockIdx.y;

  const float* Xf;
  const bf16* Wb;
  const float* bias;
  bf16* OUTb = nullptr;
  float* OUTf = nullptr;

  if (P.mode == 0) {
    const int b = z >> 2, p = z & 3;
    Xf = (p == 0 ? P.q1 : p == 1 ? P.q2 : p == 2 ? P.x1 : P.x2) + (size_t)b * CN;
    Wb = P.Wqk + ((p < 2) ? 0 : CDIM * CDIM);
    bias = (p < 2) ? P.bq : P.bk;
    OUTb = P.proj + (size_t)(p * 8 + b) * CN;
  } else {
    Wb = P.M + (size_t)z * (CDIM * CDIM);
    bias = P.Bf + z * CDIM;
    Xf = (((z >> 3) == 0) ? P.x2 : P.x1) + (size_t)(z & 7) * CN;
    OUTf = P.out + (size_t)z * CN;
  }

  const int n0 = blockIdx.x * 64;

  // X tile transposed: Xs[tok][c], stride 200 bf16 (400 B).
  // b64 writes and b128 reads are both bank-minimal at this stride with the
  // c0=(tid&15)*4 / t0=(tid>>4)*4 thread map.
  __shared__ __align__(16) bf16 Xs[64 * 200];

  {
    const int c0 = (tid & 15) * 4;
    const int t0 = (tid >> 4) * 4;
    f32x4 v[3][4];
    // issue all 12 global loads before any use (latency overlap)
#pragma unroll
    for (int cb = 0; cb < 3; cb++)
#pragma unroll
      for (int i = 0; i < 4; i++)
        v[cb][i] = *reinterpret_cast<const f32x4*>(
            Xf + (size_t)(cb * 64 + c0 + i) * NTOK + n0 + t0);
    // 4x4 register transpose + convert + vector LDS writes
#pragma unroll
    for (int cb = 0; cb < 3; cb++) {
#pragma unroll
      for (int j = 0; j < 4; j++) {
        short4v w;
        w[0] = f2bs(v[cb][0][j]);
        w[1] = f2bs(v[cb][1][j]);
        w[2] = f2bs(v[cb][2][j]);
        w[3] = f2bs(v[cb][3][j]);
        *reinterpret_cast<short4v*>(&Xs[(t0 + j) * 200 + cb * 64 + c0]) = w;
      }
    }
  }
  __syncthreads();

  const int lane = tid & 63, wave = tid >> 6;
  const int quad = lane >> 4, l15 = lane & 15;
  const int ob = wave * 48;                      // 4 waves x 48 o-rows = 192

  f32x4 acc[4][3];                               // [token-tile][o-tile]
#pragma unroll
  for (int t = 0; t < 4; t++)
#pragma unroll
    for (int ot = 0; ot < 3; ot++) acc[t][ot] = (f32x4){0.f, 0.f, 0.f, 0.f};

  const bf16* W0 = Wb + (size_t)(ob + l15) * CDIM;

#pragma unroll
  for (int ks = 0; ks < 6; ks++) {
    const int k0 = ks * 32 + quad * 8;
    short8 xf[4], wf[3];
#pragma unroll
    for (int t = 0; t < 4; t++)
      xf[t] = *reinterpret_cast<const short8*>(&Xs[(t * 16 + l15) * 200 + k0]);
#pragma unroll
    for (int ot = 0; ot < 3; ot++)
      wf[ot] = *reinterpret_cast<const short8*>(W0 + (size_t)ot * 16 * CDIM + k0);
#pragma unroll
    for (int t = 0; t < 4; t++)
#pragma unroll
      for (int ot = 0; ot < 3; ot++) acc[t][ot] = MFMA16(xf[t], wf[ot], acc[t][ot]);
  }

  // epilogue: D layout col(=o)=lane&15, row(=token)=quad*4+r -> lane holds 4
  // consecutive tokens of one o-row: vector stores.
#pragma unroll
  for (int ot = 0; ot < 3; ot++) {
    const int o = ob + ot * 16 + l15;
    const float bo = bias[o];
    if (P.mode == 0) {
      bf16* dst = OUTb + (size_t)o * NTOK + n0 + quad * 4;
#pragma unroll
      for (int t = 0; t < 4; t++) {
        short4v w;
        w[0] = f2bs(acc[t][ot][0] + bo);
        w[1] = f2bs(acc[t][ot][1] + bo);
        w[2] = f2bs(acc[t][ot][2] + bo);
        w[3] = f2bs(acc[t][ot][3] + bo);
        *reinterpret_cast<short4v*>(dst + t * 16) = w;
      }
    } else {
      float* dst = OUTf + (size_t)o * NTOK + n0 + quad * 4;
#pragma unroll
      for (int t = 0; t < 4; t++) {
        f32x4 w = {acc[t][ot][0] + bo, acc[t][ot][1] + bo,
                   acc[t][ot][2] + bo, acc[t][ot][3] + bo};
        *reinterpret_cast<f32x4*>(dst + t * 16) = w;
      }
    }
  }
}

// ---------------------------------------------------------------------------
// Gram: per (pair,b,h,ks): Z = [q_head(24); k_head(24)] rows, G += Z Z^T over
// K-slice. A-frag == B-frag layout -> 3 loads feed 9 MFMAs, no LDS in loop.
// ---------------------------------------------------------------------------
__global__ __launch_bounds__(256, 2) void gram48(const bf16* __restrict__ proj,
                                                 float* __restrict__ Gbuf) {
  const int blk = blockIdx.x;                 // 2*8*8*4 = 512
  const int ks = blk & 3, h = (blk >> 2) & 7, b = (blk >> 5) & 7, p = blk >> 8;

  const bf16* qsel = proj + (size_t)((p == 0 ? 0 : 1) * 8 + b) * CN + (size_t)h * 24 * NTOK;
  const bf16* ksel = proj + (size_t)((p == 0 ? 3 : 2) * 8 + b) * CN + (size_t)h * 24 * NTOK;

  const int tid = threadIdx.x, wave = tid >> 6, lane = tid & 63;
  const int quad = lane >> 4, l15 = lane & 15;

  const bf16* rp[3];
#pragma unroll
  for (int mt = 0; mt < 3; mt++) {
    int r = mt * 16 + l15;
    rp[mt] = (r < 24) ? qsel + (size_t)r * NTOK : ksel + (size_t)(r - 24) * NTOK;
  }

  f32x4 acc[3][3];
#pragma unroll
  for (int i = 0; i < 3; i++)
#pragma unroll
    for (int j = 0; j < 3; j++) acc[i][j] = (f32x4){0.f, 0.f, 0.f, 0.f};

  const int kend = ks * 4096 + 4096;
#pragma unroll 2
  for (int k = ks * 4096 + wave * 32 + quad * 8; k < kend; k += 128) {
    short8 f[3];
#pragma unroll
    for (int mt = 0; mt < 3; mt++) f[mt] = *reinterpret_cast<const short8*>(rp[mt] + k);
#pragma unroll
    for (int i = 0; i < 3; i++)
#pragma unroll
      for (int j = 0; j < 3; j++) acc[i][j] = MFMA16(f[i], f[j], acc[i][j]);
  }

  __shared__ float Gs[48 * 48];
  for (int i = tid; i < 2304; i += 256) Gs[i] = 0.f;
  __syncthreads();
#pragma unroll
  for (int i = 0; i < 3; i++)
#pragma unroll
    for (int j = 0; j < 3; j++)
#pragma unroll
      for (int r = 0; r < 4; r++)
        atomicAdd(&Gs[(i * 16 + quad * 4 + r) * 48 + j * 16 + l15], acc[i][j][r]);
  __syncthreads();

  float* gout = Gbuf + (size_t)((p * 8 + b) * 8 + h) * 2304;
  for (int i = tid; i < 2304; i += 256) atomicAdd(gout + i, Gs[i]);
}

// ---------------------------------------------------------------------------
// Softmax: A[c,d] = softmax_d( G[c][24+d] / (|q_c||k_d|) * scale[h] )
// ---------------------------------------------------------------------------
__global__ void attn_softmax(const float* __restrict__ Gbuf, const float* __restrict__ scale,
                             float* __restrict__ Abuf) {
  const int blk = blockIdx.x;               // (p*8+b)*8+h, 128 blocks
  const int h = blk & 7;
  const float* G = Gbuf + (size_t)blk * 2304;
  __shared__ float nrm[48];
  const int t = threadIdx.x;
  if (t < 48) nrm[t] = sqrtf(fmaxf(G[t * 48 + t], 0.f));
  __syncthreads();
  if (t < 24) {
    const float scl = scale[h];
    const float nq = fmaxf(nrm[t], 1e-12f);
    float lg[24], mx = -1e30f;
#pragma unroll
    for (int d = 0; d < 24; d++) {
      lg[d] = G[t * 48 + 24 + d] / (nq * fmaxf(nrm[24 + d], 1e-12f)) * scl;
      mx = fmaxf(mx, lg[d]);
    }
    float s = 0.f;
#pragma unroll
    for (int d = 0; d < 24; d++) { lg[d] = expf(lg[d] - mx); s += lg[d]; }
    const float inv = 1.f / s;
    float* Ao = Abuf + (size_t)blk * 576 + t * 24;
#pragma unroll
    for (int d = 0; d < 24; d++) Ao[d] = lg[d] * inv;
  }
}

// ---------------------------------------------------------------------------
// Fold: T[o,c'=h*24+d] = sum_cl Wproj[o, h*24+cl] A[h,cl,d]
//       M[o,e] = sum_c' T[o,c'] Wv[c',e]   (bf16 out for MFMA)
//       B[o]   = sum_c' T[o,c'] bv[c']
// grid: (pair*8+b)*12 + otile
// ---------------------------------------------------------------------------
__global__ __launch_bounds__(256) void fold_M(const float* __restrict__ Abuf,
                                              const float* __restrict__ Wproj,
                                              const float* __restrict__ Wv,
                                              const float* __restrict__ bv,
                                              bf16* __restrict__ Mbuf,
                                              float* __restrict__ Bbuf) {
  const int blk = blockIdx.x;
  const int pb = blk / 12, ot = blk % 12;
  const int tid = threadIdx.x;

  __shared__ float As[4608];          // 8 heads x 24 x 24
  __shared__ float Wps[3072];         // 16 o-rows x 192
  __shared__ float Ts[3072];          // 16 x 192
  __shared__ float bvs[192];

  for (int i = tid; i < 4608; i += 256) As[i] = Abuf[(size_t)pb * 4608 + i];
  for (int i = tid; i < 3072; i += 256)
    Wps[i] = Wproj[(size_t)(ot * 16 + i / 192) * CDIM + (i % 192)];
  if (tid < 192) bvs[tid] = bv[tid];
  __syncthreads();

  for (int idx = tid; idx < 3072; idx += 256) {
    const int tr = idx / 192, cp = idx % 192;
    const int h = cp / 24, d = cp % 24;
    const float* Ah = &As[h * 576 + d];          // A[h][cl][d], stride 24
    const float* Wr = &Wps[tr * 192 + h * 24];
    float s = 0.f;
#pragma unroll
    for (int cl = 0; cl < 24; cl++) s += Wr[cl] * Ah[cl * 24];
    Ts[idx] = s;
  }
  __syncthreads();

  for (int idx = tid; idx < 3072; idx += 256) {
    const int tr = idx / 192, e = idx % 192;
    const float* Tr = &Ts[tr * 192];
    float s = 0.f;
#pragma unroll 8
    for (int cp = 0; cp < 192; cp++) s += Tr[cp] * Wv[(size_t)cp * CDIM + e];
    Mbuf[((size_t)pb * CDIM + ot * 16 + tr) * CDIM + e] = f2b(s);
  }
  if (tid < 16) {
    const float* Tr = &Ts[tid * 192];
    float s = 0.f;
#pragma unroll 8
    for (int cp = 0; cp < 192; cp++) s += Tr[cp] * bvs[cp];
    Bbuf[pb * CDIM + ot * 16 + tid] = s;
  }
}

// ---------------------------------------------------------------------------
extern "C" void kernel_launch(void* const* d_in, const int* in_sizes, int n_in,
                              void* d_out, int out_size, void* d_ws, size_t ws_size,
                              hipStream_t stream) {
  const float* x1 = (const float*)d_in[0];
  const float* x2 = (const float*)d_in[1];
  const float* q1 = (const float*)d_in[2];
  const float* q2 = (const float*)d_in[3];
  const float* Wq = (const float*)d_in[4];
  const float* bq = (const float*)d_in[5];
  const float* Wk = (const float*)d_in[6];
  const float* bk = (const float*)d_in[7];
  const float* Wv = (const float*)d_in[8];
  const float* bv = (const float*)d_in[9];
  const float* scale = (const float*)d_in[10];
  const float* Wproj = (const float*)d_in[11];

  char* ws = (char*)d_ws;
  const size_t proj_bytes = (size_t)4 * 8 * CN * 2;        // 201,326,592
  const size_t gbuf_bytes = (size_t)2 * 8 * 8 * 2304 * 4;  // 1,179,648
  const size_t abuf_bytes = (size_t)2 * 8 * 8 * 576 * 4;   // 294,912
  const size_t mbuf_bytes = (size_t)16 * 192 * 192 * 2;    // 1,179,648

  bf16* proj = (bf16*)ws;
  float* Gbuf = (float*)(ws + proj_bytes);
  float* Abuf = (float*)(ws + proj_bytes + gbuf_bytes);
  bf16* Mbuf = (bf16*)(ws + proj_bytes + gbuf_bytes + abuf_bytes);
  float* Bbuf = (float*)(ws + proj_bytes + gbuf_bytes + abuf_bytes + mbuf_bytes);
  // Wqk OVERLAYS the Abuf region: Wqk (147,456 B) is consumed only by K0/K1;
  // Abuf (294,912 B) is first written by K3, after K1 completes. Lifetimes
  // are disjoint on the stream -> total ws usage identical to the verified
  // baseline layout (203,993,088 B), no growth past ws_size.
  bf16* Wqk = (bf16*)(ws + proj_bytes + gbuf_bytes);
  Wqk = (bf16*)Abuf;

  hipMemsetAsync(Gbuf, 0, gbuf_bytes, stream);

  // K0: pre-convert Wq,Wk -> bf16
  convert_w<<<dim3(72), 256, 0, stream>>>(Wq, Wk, Wqk);

  GemmParams P;
  P.q1 = q1; P.q2 = q2; P.x1 = x1; P.x2 = x2;
  P.Wqk = Wqk; P.bq = bq; P.bk = bk;
  P.proj = proj; P.M = Mbuf; P.Bf = Bbuf; P.out = (float*)d_out;
  P.mode = 0;

  // K1: 4 projections x 8 batches, 256 n-tiles of 64
  gemm_oc<<<dim3(256, 32), 256, 0, stream>>>(P);
  // K2: S + norms via stacked 48x48 Gram, K split 4
  gram48<<<dim3(512), 256, 0, stream>>>(proj, Gbuf);
  // K3: softmax -> A
  attn_softmax<<<dim3(128), 64, 0, stream>>>(Gbuf, scale, Abuf);
  // K4: fold Wproj * A_blockdiag * Wv -> M, bias
  fold_M<<<dim3(192), 256, 0, stream>>>(Abuf, Wproj, Wv, bv, Mbuf, Bbuf);
  // K5: final fused GEMM -> d_out
  GemmParams P2 = P; P2.mode = 1;
  gemm_oc<<<dim3(256, 16), 256, 0, stream>>>(P2);
}